// Round 2
// baseline (427.276 us; speedup 1.0000x reference)
//
#include <hip/hip_runtime.h>
#include <math.h>

#define N 8192
#define FIN 512
#define FOUT 256
#define NEGV (-9e15f)
#define NCAND 16
#define HMAX 16

typedef long long ll;

// async global->LDS, 16B per lane; LDS dest must be wave-uniform base + lane*16
__device__ __forceinline__ void gll16(const float* g, float* l) {
    __builtin_amdgcn_global_load_lds(
        (const __attribute__((address_space(1))) unsigned int*)g,
        (__attribute__((address_space(3))) unsigned int*)l,
        16, 0, 0);
}

// ---------------- kernel 1: Wh = h @ W (8192x512x256 f32) ----------------
// 256 threads, 64x64 tile, 4x4/thread (verified mapping, bit-exact fmaf chains).
// B staged via global_load_lds into a double-buffered unpadded [32][64] tile;
// A staged through registers (transposed store) as before.
__global__ __launch_bounds__(256) void wh_gemm(const float* __restrict__ A,
                                               const float* __restrict__ B,
                                               float* __restrict__ C,
                                               unsigned* __restrict__ gmaxbits) {
    __shared__ float As[32][68];
    __shared__ float Bs[2][32][64];
    const int tid = threadIdx.x;
    if (blockIdx.x == 0 && blockIdx.y == 0 && tid == 0) *gmaxbits = 0u;
    const int m0 = blockIdx.y * 64, n0 = blockIdx.x * 64;
    const int tx = tid & 15, ty = tid >> 4;
    const int arow = tid >> 2, ak = (tid & 3) * 8;   // A: 64 rows x 32 k
    const int bk = tid >> 4, bn4 = tid & 15;         // B float4 idx4 = tid -> (k, n/4)
    const float* aptr = &A[(m0 + arow) * FIN + ak];
    const float* bg0 = &B[bk * FOUT + n0 + bn4 * 4];          // k rows 0..15
    const float* bg1 = &B[(bk + 16) * FOUT + n0 + bn4 * 4];   // k rows 16..31
    // wave-uniform LDS bases (lane placement is implicit: +lane*16B)
    float* l0 = &Bs[0][0][0] + (tid >> 6) * 256;
    gll16(bg0, l0);
    gll16(bg1, l0 + 1024);
    float4 av0 = *(const float4*)aptr, av1 = *(const float4*)(aptr + 4);
    float acc[4][4] = {};
    int buf = 0;
    for (int k0 = 0; k0 < FIN; k0 += 32) {
        As[ak + 0][arow] = av0.x; As[ak + 1][arow] = av0.y;
        As[ak + 2][arow] = av0.z; As[ak + 3][arow] = av0.w;
        As[ak + 4][arow] = av1.x; As[ak + 5][arow] = av1.y;
        As[ak + 6][arow] = av1.z; As[ak + 7][arow] = av1.w;
        __syncthreads();                       // As ready; drains gll -> Bs[buf] ready
        if (k0 + 32 < FIN) {                   // prefetch next tile during compute
            aptr += 32;
            av0 = *(const float4*)aptr; av1 = *(const float4*)(aptr + 4);
            bg0 += 32 * FOUT; bg1 += 32 * FOUT;
            float* nl = &Bs[buf ^ 1][0][0] + (tid >> 6) * 256;
            gll16(bg0, nl);
            gll16(bg1, nl + 1024);
        }
        const float* Bc = &Bs[buf][0][0];
#pragma unroll
        for (int k = 0; k < 32; ++k) {
            float4 a = *(const float4*)&As[k][4 * ty];
            float4 b = *(const float4*)&Bc[k * 64 + 4 * tx];
            float ar[4] = {a.x, a.y, a.z, a.w};
            float br[4] = {b.x, b.y, b.z, b.w};
#pragma unroll
            for (int i = 0; i < 4; ++i)
#pragma unroll
                for (int j = 0; j < 4; ++j)
                    acc[i][j] = fmaf(ar[i], br[j], acc[i][j]);
        }
        __syncthreads();
        buf ^= 1;
    }
#pragma unroll
    for (int i = 0; i < 4; ++i) {
        float4 v = make_float4(acc[i][0], acc[i][1], acc[i][2], acc[i][3]);
        *(float4*)&C[(m0 + 4 * ty + i) * FOUT + n0 + 4 * tx] = v;
    }
}

// ---------------- kernel 2: per-row factors + t1 + norms + nrm-max + slice top-16 ----------------
// Fusion of factors2_kernel + redtopk1_kernel. 64 blocks x 256 threads; each block owns
// 128 rows; wave 0 then runs the identical nrm-max + top-16 comparator from LDS.
__global__ __launch_bounds__(256) void factors_top_kernel(
    const float* __restrict__ Wh, const float* __restrict__ Mui,
    float* __restrict__ params,
    float* __restrict__ t1a, float* __restrict__ x1, float* __restrict__ x2,
    float* __restrict__ w1, float* __restrict__ w2, float* __restrict__ nrm,
    unsigned* __restrict__ gmaxbits, float* __restrict__ o1v, int* __restrict__ o1i) {
    __shared__ float sT1[128];
    __shared__ float sNrm[128];
    const int t = threadIdx.x, w = t >> 6, lane = t & 63;
    const int base = blockIdx.x * 128;
    // mui softmax in-register (identical expressions to verified path)
    float m = Mui[0];
    for (int q = 1; q < 6; ++q) m = fmaxf(m, Mui[q]);
    float e[6], es = 0.f;
    for (int q = 0; q < 6; ++q) { e[q] = expf(Mui[q] - m); es += e[q]; }
    float mui[6];
    for (int q = 0; q < 6; ++q) mui[q] = e[q] / es;
    const float p2 = 256.0f * mui[4], p3 = 256.0f * mui[5];
    if (blockIdx.x == 0 && t == 0) {
        params[0] = mui[0] + mui[1] + mui[2] + mui[3];
        params[1] = 0.5f * (mui[0] + mui[1]) + 1.0f * (mui[2] + mui[3]);
        params[2] = p2;
        params[3] = p3;
    }
    for (int r = 0; r < 32; ++r) {
        const int row = base + r * 4 + w;      // 4 waves read 4 consecutive rows
        float4 v = ((const float4*)&Wh[(ll)row * FOUT])[lane];
        float s = v.x * v.x + v.y * v.y + v.z * v.z + v.w * v.w;
#pragma unroll
        for (int off = 1; off < 64; off <<= 1) s += __shfl_xor(s, off, 64);
        if (lane == 0) {
            float nr = sqrtf(s);
            nrm[row] = nr; sNrm[r * 4 + w] = nr;
            float tt = Wh[(ll)row * FOUT + 1];
            float t1 = tt * tt;                // exact same expr as verified path
            t1a[row] = t1; sT1[r * 4 + w] = t1;
            x1[row] = expf(0.5f * t1);
            x2[row] = expf(t1);
            w1[row] = p2 * expf(-0.5f * t1);
            w2[row] = p3 * expf(-t1);
        }
    }
    __syncthreads();
    if (w == 0) {
        // nrm max over this block's 128 rows -> 64 atomics chip-wide
        float nm = fmaxf(sNrm[lane], sNrm[64 + lane]);
#pragma unroll
        for (int off = 1; off < 64; off <<= 1) nm = fmaxf(nm, __shfl_xor(nm, off, 64));
        if (lane == 0) atomicMax(gmaxbits, __float_as_uint(nm));   // nrm > 0 -> bit-monotone
        // per-slice top-16 of t1 (desc value, asc index) — identical comparator
        float v0 = sT1[lane], v1 = sT1[64 + lane];
        int i0 = base + lane, i1 = base + 64 + lane;
        for (int r = 0; r < NCAND; ++r) {
            float mv; int mi;
            if (v0 >= v1) { mv = v0; mi = i0; } else { mv = v1; mi = i1; }
#pragma unroll
            for (int off = 1; off < 64; off <<= 1) {
                float ov = __shfl_xor(mv, off, 64);
                int   oi = __shfl_xor(mi, off, 64);
                if (ov > mv || (ov == mv && oi < mi)) { mv = ov; mi = oi; }
            }
            if (mi == i0) v0 = -2.f;
            if (mi == i1) v1 = -2.f;
            if (lane == r) { o1v[blockIdx.x * NCAND + r] = mv; o1i[blockIdx.x * NCAND + r] = mi; }
        }
    }
}

// ---------------- kernel 3b: global top-16 + hard init + celu table (1 block) ----------------
// Each slice's 16-entry list is sorted (desc value, asc index) by construction, so the
// global top-16 is a 64-way sorted-list merge: one wave, 16 rounds, no block barriers.
__global__ __launch_bounds__(1024) void topk2_kernel(
    const float* __restrict__ o1v, const int* __restrict__ o1i,
    const float* __restrict__ t1a, const float* __restrict__ x1, const float* __restrict__ x2,
    const float* __restrict__ Wh,
    int* __restrict__ cidx, float* __restrict__ ct1, float* __restrict__ cx1,
    float* __restrict__ cx2, float* __restrict__ ubx, int* __restrict__ hardcnt,
    float* __restrict__ acc, float* __restrict__ rowsum, unsigned* __restrict__ rowmaxenc,
    float* __restrict__ celu) {
    __shared__ float sv[1024];
    __shared__ int   si[1024];
    __shared__ int   scidx[NCAND];
    const int t = threadIdx.x;
#pragma unroll
    for (int q = 0; q < HMAX * FOUT / 1024; ++q) acc[q * 1024 + t] = 0.f;
    if (t < HMAX) { rowsum[t] = 0.f; rowmaxenc[t] = 0u; }
    sv[t] = o1v[t];
    si[t] = o1i[t];
    __syncthreads();
    if (t < 64) {
        int h = 0;                                   // head into my sorted 16-entry slice list
        float hv = sv[t << 4];
        int   hi = si[t << 4];
        for (int r = 0; r < NCAND; ++r) {
            float mv = hv; int mi = hi;
#pragma unroll
            for (int off = 1; off < 64; off <<= 1) {
                float ov = __shfl_xor(mv, off, 64);
                int   oi = __shfl_xor(mi, off, 64);
                if (ov > mv || (ov == mv && oi < mi)) { mv = ov; mi = oi; }
            }
            if (t == r) cidx[r] = mi;                // global (for classify_kernel)
            if (t == 0) scidx[r] = mi;               // shared (for this kernel's tail)
            if (mi == hi) {                          // my head won -> advance
                ++h;
                if (h < NCAND) { hv = sv[(t << 4) + h]; hi = si[(t << 4) + h]; }
                else           { hv = -1e30f; hi = 0x7fffffff; }   // exhausted: always loses
            }
        }
    }
    __syncthreads();
    if (t < NCAND) {
        int j = scidx[t];
        ct1[t] = t1a[j];
        cx1[t] = x1[j];
        cx2[t] = x2[j];
    }
    if (t == 0) {
        int j = scidx[NCAND - 1];
        ubx[0] = x1[j];
        ubx[1] = x2[j];
        *hardcnt = 0;
    }
    // celu[q] = ELU(Wh[cidx[q]]) — 16 rows x 64 float4 = exactly 1024 threads
    {
        const int q = t >> 6, cc = (t & 63) * 4;
        const int row = scidx[q];
        float4 w = *(const float4*)&Wh[(ll)row * FOUT + cc];
        w.x = w.x > 0.f ? w.x : expm1f(w.x);
        w.y = w.y > 0.f ? w.y : expm1f(w.y);
        w.z = w.z > 0.f ? w.z : expm1f(w.z);
        w.w = w.w > 0.f ? w.w : expm1f(w.w);
        *(float4*)&celu[q * FOUT + cc] = w;
    }
}

// ---------------- kernel 4: classify rows; write easy rows (one wave per row) ----------------
__global__ __launch_bounds__(256) void classify_kernel(
    const float* __restrict__ celu, const float* __restrict__ params,
    const int* __restrict__ adj, const int* __restrict__ cidx,
    const float* __restrict__ ct1, const float* __restrict__ cx1, const float* __restrict__ cx2,
    const float* __restrict__ ubx, const float* __restrict__ w1, const float* __restrict__ w2,
    const float* __restrict__ nrm, const unsigned* __restrict__ gmaxbits,
    int* __restrict__ hardcnt, int* __restrict__ hardlist, float* __restrict__ out) {
    const int i = (blockIdx.x << 2) + (threadIdx.x >> 6);   // one 64-lane wave per row
    const int lane = threadIdx.x & 63;
    const bool valid = lane < NCAND;

    int   cj  = valid ? cidx[lane] : 0;
    float cT  = valid ? ct1[lane] : -1.f;
    float cX1 = valid ? cx1[lane] : 0.f;
    float cX2 = valid ? cx2[lane] : 0.f;
    int ad = valid ? adj[(ll)i * N + cj] : 0;
    unsigned long long m = __ballot(ad > 0);

    float w1i = w1[i], w2i = w2[i];
    bool hard = false;
    int f = -1;
    if (m == 0ull) {
        hard = true;   // no adjacent candidate (incl. all-zero adj row) -> exact fallback
    } else {
        f = __ffsll(m) - 1;
        float t1f = __shfl(cT, f, 64);
        float x1f = __shfl(cX1, f, 64);
        float x2f = __shfl(cX2, f, 64);
        float lastT = __shfl(cT, NCAND - 1, 64);
        // tie on t1 bits among adjacent candidates -> reference may average -> fallback;
        // tie with the candidate-list boundary value -> off-list tie possible -> fallback
        unsigned long long tm = __ballot(ad > 0 && (cT == t1f));
        if (__popcll(tm) > 1 || t1f == lastT) hard = true;
        float Lx1 = w1i * x1f + w2i * x2f;
        unsigned long long m2 = m & ~(1ull << f);
        float Lx2 = -INFINITY;
        if (m2 != 0ull) {
            int s2 = __ffsll(m2) - 1;
            Lx2 = w1i * __shfl(cX1, s2, 64) + w2i * __shfl(cX2, s2, 64);
        }
        float ub  = w1i * ubx[0] + w2i * ubx[1];   // bound for ALL non-candidate columns
        float alt = fmaxf(Lx2, ub);
        float gmax = __uint_as_float(*gmaxbits);
        float margin = 2.0f * params[0] * nrm[i] * gmax + 100.0f + 1e-5f * Lx1;
        if (!(Lx1 - alt > margin)) hard = true;    // NaN-safe: NaN -> hard
    }
    if (hard) {
        if (lane == 0) { int p = atomicAdd(hardcnt, 1); hardlist[p] = i; }
        return;
    }
    // easy: softmax exactly one-hot at candidate rank f -> out = celu[f] (precomputed)
    float4 v = ((const float4*)&celu[(ll)f * FOUT])[lane];
    ((float4*)&out[(ll)i * FOUT])[lane] = v;
}

// ---------------- kernel 5a: hard rows — logits + row max (parallel over chunks) ----------------
__global__ __launch_bounds__(256) void hardA_kernel(
    const float* __restrict__ Wh, const float* __restrict__ params,
    const int* __restrict__ adj, const float* __restrict__ x1, const float* __restrict__ x2,
    const float* __restrict__ w1, const float* __restrict__ w2,
    const int* __restrict__ hardcnt, const int* __restrict__ hardlist,
    float* __restrict__ ebuf, unsigned* __restrict__ rowmaxenc) {
    const int h = blockIdx.x >> 5;          // 32 chunks of 256 columns
    const int chunk = blockIdx.x & 31;
    const int nh = min(*hardcnt, HMAX);
    if (h >= nh) return;
    const int i = hardlist[h];
    __shared__ float Whi[FOUT];
    __shared__ float red[4];
    const int t = threadIdx.x;
    Whi[t] = Wh[(ll)i * FOUT + t];
    __syncthreads();
    const int j = (chunk << 8) + t;
    const float4* wi4 = (const float4*)Whi;
    const float4* wr  = (const float4*)&Wh[(ll)j * FOUT];
    float s = 0.f;
#pragma unroll 8
    for (int f = 0; f < 64; ++f) {
        float4 a = wi4[f], b = wr[f];
        s = fmaf(a.x, b.x, fmaf(a.y, b.y, fmaf(a.z, b.z, fmaf(a.w, b.w, s))));
    }
    float ev = fmaf(params[0], s, params[1]);
    ev = fmaf(w1[i], x1[j], ev);
    ev = fmaf(w2[i], x2[j], ev);
    ev = (adj[(ll)i * N + j] > 0) ? ev : NEGV;
    ebuf[h * N + j] = ev;
    float mx = ev;
#pragma unroll
    for (int off = 1; off < 64; off <<= 1) mx = fmaxf(mx, __shfl_xor(mx, off, 64));
    if ((t & 63) == 0) red[t >> 6] = mx;
    __syncthreads();
    if (t == 0) {
        mx = fmaxf(fmaxf(red[0], red[1]), fmaxf(red[2], red[3]));
        unsigned u = __float_as_uint(mx);
        unsigned enc = (u & 0x80000000u) ? ~u : (u | 0x80000000u);
        atomicMax(&rowmaxenc[h], enc);
    }
}

// ---------------- kernel 5b: hard rows — exp/sum + partial PV ----------------
__global__ __launch_bounds__(256) void hardB_kernel(
    const float* __restrict__ Wh, const int* __restrict__ hardcnt,
    const float* __restrict__ ebuf, const unsigned* __restrict__ rowmaxenc,
    float* __restrict__ rowsum, float* __restrict__ acc) {
    const int h = blockIdx.x >> 5;
    const int chunk = blockIdx.x & 31;
    const int nh = min(*hardcnt, HMAX);
    if (h >= nh) return;
    const int t = threadIdx.x;
    unsigned enc = rowmaxenc[h];
    unsigned u = (enc & 0x80000000u) ? (enc & 0x7fffffffu) : ~enc;
    const float mx = __uint_as_float(u);
    const int j = (chunk << 8) + t;
    float p = expf(ebuf[h * N + j] - mx);
    __shared__ float pl[256];
    pl[t] = p;
    float ps = p;
#pragma unroll
    for (int off = 1; off < 64; off <<= 1) ps += __shfl_xor(ps, off, 64);
    if ((t & 63) == 0) atomicAdd(&rowsum[h], ps);
    __syncthreads();
    float o = 0.f;
    const float* base = &Wh[(ll)(chunk << 8) * FOUT + t];
#pragma unroll 4
    for (int jj = 0; jj < 256; ++jj) o = fmaf(pl[jj], base[(ll)jj * FOUT], o);
    atomicAdd(&acc[h * FOUT + t], o);
}

// ---------------- kernel 5c: hard rows — normalize+store (blocks<HMAX) + serial overflow tail ----------------
__global__ __launch_bounds__(256) void hardCtail_kernel(
    const float* __restrict__ Wh, const float* __restrict__ params,
    const int* __restrict__ adj, const float* __restrict__ x1, const float* __restrict__ x2,
    const float* __restrict__ w1, const float* __restrict__ w2,
    const int* __restrict__ hardcnt, const int* __restrict__ hardlist,
    const float* __restrict__ rowsum, const float* __restrict__ acc,
    float* __restrict__ out) {
    __shared__ float Whi[FOUT];
    __shared__ float ebuf[N];
    __shared__ float red[16];
    const int t = threadIdx.x;
    const int nh = *hardcnt;
    if (blockIdx.x < HMAX) {
        const int h = blockIdx.x;
        if (h >= min(nh, HMAX)) return;
        const int i = hardlist[h];
        float o = acc[h * FOUT + t] / rowsum[h];
        out[(ll)i * FOUT + t] = o > 0.f ? o : expm1f(o);
        return;
    }
    // overflow tail: h >= HMAX (normally no-op)
    for (int h = HMAX + (blockIdx.x - HMAX); h < nh; h += gridDim.x - HMAX) {
        const int i = hardlist[h];
        __syncthreads();
        Whi[t] = Wh[(ll)i * FOUT + t];
        __syncthreads();
        const float aC = params[0], cA = params[1], w1i = w1[i], w2i = w2[i];
        const float4* wi4 = (const float4*)Whi;
        for (int j0 = 0; j0 < N; j0 += 256) {
            int j = j0 + t;
            const float4* wr = (const float4*)&Wh[(ll)j * FOUT];
            float s = 0.f;
#pragma unroll 8
            for (int f = 0; f < 64; ++f) {
                float4 a = wi4[f], b = wr[f];
                s = fmaf(a.x, b.x, fmaf(a.y, b.y, fmaf(a.z, b.z, fmaf(a.w, b.w, s))));
            }
            float ev = fmaf(aC, s, cA);
            ev = fmaf(w1i, x1[j], ev);
            ev = fmaf(w2i, x2[j], ev);
            ebuf[j] = (adj[(ll)i * N + j] > 0) ? ev : NEGV;
        }
        __syncthreads();
        float mx = -INFINITY;
        for (int j = t; j < N; j += 256) mx = fmaxf(mx, ebuf[j]);
#pragma unroll
        for (int off = 1; off < 64; off <<= 1) mx = fmaxf(mx, __shfl_xor(mx, off, 64));
        if ((t & 63) == 0) red[t >> 6] = mx;
        __syncthreads();
        mx = fmaxf(fmaxf(red[0], red[1]), fmaxf(red[2], red[3]));
        float ls = 0.f;
        for (int j = t; j < N; j += 256) {
            float p = expf(ebuf[j] - mx);
            ebuf[j] = p;
            ls += p;
        }
#pragma unroll
        for (int off = 1; off < 64; off <<= 1) ls += __shfl_xor(ls, off, 64);
        if ((t & 63) == 0) red[8 + (t >> 6)] = ls;
        __syncthreads();
        ls = (red[8] + red[9]) + (red[10] + red[11]);
        float o0 = 0.f, o1 = 0.f, o2 = 0.f, o3 = 0.f;
        for (int j = 0; j < N; j += 4) {
            o0 = fmaf(ebuf[j + 0], Wh[(ll)(j + 0) * FOUT + t], o0);
            o1 = fmaf(ebuf[j + 1], Wh[(ll)(j + 1) * FOUT + t], o1);
            o2 = fmaf(ebuf[j + 2], Wh[(ll)(j + 2) * FOUT + t], o2);
            o3 = fmaf(ebuf[j + 3], Wh[(ll)(j + 3) * FOUT + t], o3);
        }
        float o = ((o0 + o1) + (o2 + o3)) / ls;
        out[(ll)i * FOUT + t] = o > 0.f ? o : expm1f(o);
    }
}

// ---------------- launch ----------------
extern "C" void kernel_launch(void* const* d_in, const int* in_sizes, int n_in,
                              void* d_out, int out_size, void* d_ws, size_t ws_size,
                              hipStream_t stream) {
    const float* h   = (const float*)d_in[0];
    const float* W   = (const float*)d_in[1];
    const float* Mui = (const float*)d_in[2];
    const int*   adj = (const int*)d_in[3];
    float* out = (float*)d_out;

    float* ws = (float*)d_ws;
    float* Wh     = ws;                         // 8192*256
    float* t1a    = Wh + N * FOUT;              // N
    float* x1     = t1a + N;
    float* x2     = x1 + N;
    float* w1     = x2 + N;
    float* w2     = w1 + N;
    float* nrm    = w2 + N;
    float* params = nrm + N;                    // 8
    float* ct1    = params + 8;                 // NCAND
    float* cx1    = ct1 + NCAND;
    float* cx2    = cx1 + NCAND;
    float* ubx    = cx2 + NCAND;                // 2
    float* o1v    = ubx + 2;                    // 1024
    float* celu   = o1v + 1024;                 // NCAND*FOUT = 4096
    float* ebuf   = celu + NCAND * FOUT;        // HMAX*N
    float* acc    = ebuf + HMAX * N;            // HMAX*FOUT
    float* rowsum = acc + HMAX * FOUT;          // HMAX
    int*   o1i       = (int*)(rowsum + HMAX);   // 1024
    int*   cidx      = o1i + 1024;              // NCAND
    int*   hardcnt   = cidx + NCAND;            // 1
    unsigned* gmaxb  = (unsigned*)(hardcnt + 1);// 1
    unsigned* rowmaxenc = gmaxb + 1;            // HMAX
    int*   hardlist  = (int*)(rowmaxenc + HMAX);// N

    wh_gemm<<<dim3(FOUT / 64, N / 64), 256, 0, stream>>>(h, W, Wh, gmaxb);
    factors_top_kernel<<<64, 256, 0, stream>>>(Wh, Mui, params, t1a, x1, x2, w1, w2, nrm,
                                               gmaxb, o1v, o1i);
    topk2_kernel<<<1, 1024, 0, stream>>>(o1v, o1i, t1a, x1, x2, Wh,
                                         cidx, ct1, cx1, cx2, ubx, hardcnt,
                                         acc, rowsum, rowmaxenc, celu);
    classify_kernel<<<N / 4, 256, 0, stream>>>(celu, params, adj, cidx, ct1, cx1, cx2, ubx,
                                               w1, w2, nrm, gmaxb, hardcnt, hardlist, out);
    hardA_kernel<<<32 * HMAX, 256, 0, stream>>>(Wh, params, adj, x1, x2, w1, w2,
                                                hardcnt, hardlist, ebuf, rowmaxenc);
    hardB_kernel<<<32 * HMAX, 256, 0, stream>>>(Wh, hardcnt, ebuf, rowmaxenc, rowsum, acc);
    hardCtail_kernel<<<HMAX + 128, 256, 0, stream>>>(Wh, params, adj, x1, x2, w1, w2,
                                                     hardcnt, hardlist, rowsum, acc, out);
    (void)n_in; (void)in_sizes; (void)out_size; (void)ws_size;
}

// Round 3
// 414.598 us; speedup vs baseline: 1.0306x; 1.0306x over previous
//
#include <hip/hip_runtime.h>
#include <math.h>

#define N 8192
#define FIN 512
#define FOUT 256
#define NEGV (-9e15f)
#define NCAND 16
#define HMAX 16

typedef long long ll;

// ---------------- kernel 1: Wh = h @ W (8192x512x256 f32), double-buffered ----------------
__global__ __launch_bounds__(256) void wh_gemm(const float* __restrict__ A,
                                               const float* __restrict__ B,
                                               float* __restrict__ C,
                                               unsigned* __restrict__ gmaxbits) {
    __shared__ float As[32][68];
    __shared__ float Bs[32][68];
    const int tid = threadIdx.x;
    if (blockIdx.x == 0 && blockIdx.y == 0 && tid == 0) *gmaxbits = 0u;
    const int m0 = blockIdx.y * 64, n0 = blockIdx.x * 64;
    const int tx = tid & 15, ty = tid >> 4;
    const int arow = tid >> 2, ak = (tid & 3) * 8;   // A: 64 rows x 32 k
    const int brow = tid >> 3, bn = (tid & 7) * 8;   // B: 32 k x 64 n
    const float* aptr = &A[(m0 + arow) * FIN + ak];
    const float* bptr = &B[brow * FOUT + n0 + bn];
    float4 av0 = *(const float4*)aptr, av1 = *(const float4*)(aptr + 4);
    float4 bv0 = *(const float4*)bptr, bv1 = *(const float4*)(bptr + 4);
    float acc[4][4] = {};
    for (int k0 = 0; k0 < FIN; k0 += 32) {
        As[ak + 0][arow] = av0.x; As[ak + 1][arow] = av0.y;
        As[ak + 2][arow] = av0.z; As[ak + 3][arow] = av0.w;
        As[ak + 4][arow] = av1.x; As[ak + 5][arow] = av1.y;
        As[ak + 6][arow] = av1.z; As[ak + 7][arow] = av1.w;
        *(float4*)&Bs[brow][bn] = bv0;
        *(float4*)&Bs[brow][bn + 4] = bv1;
        __syncthreads();
        if (k0 + 32 < FIN) {   // prefetch next tile while this one computes
            aptr += 32; bptr += 32 * FOUT;
            av0 = *(const float4*)aptr; av1 = *(const float4*)(aptr + 4);
            bv0 = *(const float4*)bptr; bv1 = *(const float4*)(bptr + 4);
        }
#pragma unroll
        for (int k = 0; k < 32; ++k) {
            float4 a = *(const float4*)&As[k][4 * ty];
            float4 b = *(const float4*)&Bs[k][4 * tx];
            float ar[4] = {a.x, a.y, a.z, a.w};
            float br[4] = {b.x, b.y, b.z, b.w};
#pragma unroll
            for (int i = 0; i < 4; ++i)
#pragma unroll
                for (int j = 0; j < 4; ++j)
                    acc[i][j] = fmaf(ar[i], br[j], acc[i][j]);
        }
        __syncthreads();
    }
#pragma unroll
    for (int i = 0; i < 4; ++i) {
        float4 v = make_float4(acc[i][0], acc[i][1], acc[i][2], acc[i][3]);
        *(float4*)&C[(m0 + 4 * ty + i) * FOUT + n0 + 4 * tx] = v;
    }
}

// ---------------- kernel 2: per-row factors + t1 + norms (no global atomics) ----------------
__global__ __launch_bounds__(256) void factors2_kernel(
    const float* __restrict__ Wh, const float* __restrict__ Mui,
    float* __restrict__ params,
    float* __restrict__ t1a, float* __restrict__ x1, float* __restrict__ x2,
    float* __restrict__ w1, float* __restrict__ w2,
    float* __restrict__ nrm) {
    const int t = threadIdx.x;
    const int lane = t & 63;
    const int i = blockIdx.x * 4 + (t >> 6);
    float4 v = ((const float4*)&Wh[(ll)i * FOUT])[lane];
    float s = v.x * v.x + v.y * v.y + v.z * v.z + v.w * v.w;
#pragma unroll
    for (int off = 1; off < 64; off <<= 1) s += __shfl_xor(s, off, 64);
    if (lane == 0) {
        // recompute mui softmax in-register (identical expressions to verified R2 path)
        float m = Mui[0];
        for (int q = 1; q < 6; ++q) m = fmaxf(m, Mui[q]);
        float e[6], es = 0.f;
        for (int q = 0; q < 6; ++q) { e[q] = expf(Mui[q] - m); es += e[q]; }
        float mui[6];
        for (int q = 0; q < 6; ++q) mui[q] = e[q] / es;
        float p2 = 256.0f * mui[4], p3 = 256.0f * mui[5];
        if (i == 0) {
            params[0] = mui[0] + mui[1] + mui[2] + mui[3];
            params[1] = 0.5f * (mui[0] + mui[1]) + 1.0f * (mui[2] + mui[3]);
            params[2] = p2;
            params[3] = p3;
        }
        nrm[i] = sqrtf(s);
        float tt = Wh[(ll)i * FOUT + 1];
        float t1 = tt * tt;                          // exact same expr as verified R2 kernel
        t1a[i] = t1;
        x1[i] = expf(0.5f * t1);
        x2[i] = expf(t1);
        w1[i] = p2 * expf(-0.5f * t1);
        w2[i] = p3 * expf(-t1);
    }
}

// ---------------- kernel 3a: fused nrm-max + per-slice top-16 (64 blocks x 1 wave) ----------------
__global__ __launch_bounds__(64) void redtopk1_kernel(const float* __restrict__ t1a,
                                                      const float* __restrict__ nrm,
                                                      unsigned* __restrict__ gmaxbits,
                                                      float* __restrict__ o1v,
                                                      int* __restrict__ o1i) {
    const int l = threadIdx.x;
    const int base = blockIdx.x * 128;
    // nrm max over this block's 128 rows -> 64 atomics chip-wide
    float nm = fmaxf(nrm[base + l], nrm[base + 64 + l]);
#pragma unroll
    for (int off = 1; off < 64; off <<= 1) nm = fmaxf(nm, __shfl_xor(nm, off, 64));
    if (l == 0) atomicMax(gmaxbits, __float_as_uint(nm));   // nrm > 0 -> bit-monotone
    // per-slice top-16 of t1
    float v0 = t1a[base + l], v1 = t1a[base + 64 + l];
    int i0 = base + l, i1 = base + 64 + l;
    for (int r = 0; r < NCAND; ++r) {
        float mv; int mi;
        if (v0 >= v1) { mv = v0; mi = i0; } else { mv = v1; mi = i1; }
#pragma unroll
        for (int off = 1; off < 64; off <<= 1) {
            float ov = __shfl_xor(mv, off, 64);
            int   oi = __shfl_xor(mi, off, 64);
            if (ov > mv || (ov == mv && oi < mi)) { mv = ov; mi = oi; }
        }
        if (mi == i0) v0 = -2.f;
        if (mi == i1) v1 = -2.f;
        if (l == r) { o1v[blockIdx.x * NCAND + r] = mv; o1i[blockIdx.x * NCAND + r] = mi; }
    }
}

// ---------------- kernel 3b: global top-16 + hard init + celu table (1 block) ----------------
__global__ __launch_bounds__(1024) void topk2_kernel(
    const float* __restrict__ o1v, const int* __restrict__ o1i,
    const float* __restrict__ t1a, const float* __restrict__ x1, const float* __restrict__ x2,
    const float* __restrict__ Wh,
    int* __restrict__ cidx, float* __restrict__ ct1, float* __restrict__ cx1,
    float* __restrict__ cx2, float* __restrict__ ubx, int* __restrict__ hardcnt,
    float* __restrict__ acc, float* __restrict__ rowsum, unsigned* __restrict__ rowmaxenc,
    float* __restrict__ celu) {
    __shared__ float lv[16];
    __shared__ int li[16];
    __shared__ float bvs;
    __shared__ int bis;
    const int t = threadIdx.x;
#pragma unroll
    for (int q = 0; q < HMAX * FOUT / 1024; ++q) acc[q * 1024 + t] = 0.f;
    if (t < HMAX) { rowsum[t] = 0.f; rowmaxenc[t] = 0u; }
    float v = o1v[t];
    int idx = o1i[t];
    for (int r = 0; r < NCAND; ++r) {
        float mv = v; int mi = idx;
#pragma unroll
        for (int off = 1; off < 64; off <<= 1) {
            float ov = __shfl_xor(mv, off, 64);
            int   oi = __shfl_xor(mi, off, 64);
            if (ov > mv || (ov == mv && oi < mi)) { mv = ov; mi = oi; }
        }
        if ((t & 63) == 0) { lv[t >> 6] = mv; li[t >> 6] = mi; }
        __syncthreads();
        if (t < 64) {
            float m2 = (t < 16) ? lv[t] : -3.f;
            int   i2 = (t < 16) ? li[t] : -1;
#pragma unroll
            for (int off = 1; off < 16; off <<= 1) {
                float ov = __shfl_xor(m2, off, 64);
                int   oi = __shfl_xor(i2, off, 64);
                if (ov > m2 || (ov == m2 && oi < i2)) { m2 = ov; i2 = oi; }
            }
            if (t == 0) { bvs = m2; bis = i2; }
        }
        __syncthreads();
        if (idx == bis) v = -2.f;
        if (t == r) cidx[r] = bis;
    }
    __syncthreads();
    if (t < NCAND) {
        int j = cidx[t];
        ct1[t] = t1a[j];
        cx1[t] = x1[j];
        cx2[t] = x2[j];
    }
    if (t == 0) {
        int j = cidx[NCAND - 1];
        ubx[0] = x1[j];
        ubx[1] = x2[j];
        *hardcnt = 0;
    }
    // celu[q] = ELU(Wh[cidx[q]]) — 16 rows x 64 float4 = exactly 1024 threads
    {
        const int q = t >> 6, cc = (t & 63) * 4;
        const int row = cidx[q];
        float4 w = *(const float4*)&Wh[(ll)row * FOUT + cc];
        w.x = w.x > 0.f ? w.x : expm1f(w.x);
        w.y = w.y > 0.f ? w.y : expm1f(w.y);
        w.z = w.z > 0.f ? w.z : expm1f(w.z);
        w.w = w.w > 0.f ? w.w : expm1f(w.w);
        *(float4*)&celu[q * FOUT + cc] = w;
    }
}

// ---------------- kernel 4: classify rows; write easy rows (one wave per row) ----------------
__global__ __launch_bounds__(256) void classify_kernel(
    const float* __restrict__ celu, const float* __restrict__ params,
    const int* __restrict__ adj, const int* __restrict__ cidx,
    const float* __restrict__ ct1, const float* __restrict__ cx1, const float* __restrict__ cx2,
    const float* __restrict__ ubx, const float* __restrict__ w1, const float* __restrict__ w2,
    const float* __restrict__ nrm, const unsigned* __restrict__ gmaxbits,
    int* __restrict__ hardcnt, int* __restrict__ hardlist, float* __restrict__ out) {
    const int i = (blockIdx.x << 2) + (threadIdx.x >> 6);   // one 64-lane wave per row
    const int lane = threadIdx.x & 63;
    const bool valid = lane < NCAND;

    int   cj  = valid ? cidx[lane] : 0;
    float cT  = valid ? ct1[lane] : -1.f;
    float cX1 = valid ? cx1[lane] : 0.f;
    float cX2 = valid ? cx2[lane] : 0.f;
    int ad = valid ? adj[(ll)i * N + cj] : 0;
    unsigned long long m = __ballot(ad > 0);

    float w1i = w1[i], w2i = w2[i];
    bool hard = false;
    int f = -1;
    if (m == 0ull) {
        hard = true;   // no adjacent candidate (incl. all-zero adj row) -> exact fallback
    } else {
        f = __ffsll(m) - 1;
        float t1f = __shfl(cT, f, 64);
        float x1f = __shfl(cX1, f, 64);
        float x2f = __shfl(cX2, f, 64);
        float lastT = __shfl(cT, NCAND - 1, 64);
        // tie on t1 bits among adjacent candidates -> reference may average -> fallback;
        // tie with the candidate-list boundary value -> off-list tie possible -> fallback
        unsigned long long tm = __ballot(ad > 0 && (cT == t1f));
        if (__popcll(tm) > 1 || t1f == lastT) hard = true;
        float Lx1 = w1i * x1f + w2i * x2f;
        unsigned long long m2 = m & ~(1ull << f);
        float Lx2 = -INFINITY;
        if (m2 != 0ull) {
            int s2 = __ffsll(m2) - 1;
            Lx2 = w1i * __shfl(cX1, s2, 64) + w2i * __shfl(cX2, s2, 64);
        }
        float ub  = w1i * ubx[0] + w2i * ubx[1];   // bound for ALL non-candidate columns
        float alt = fmaxf(Lx2, ub);
        float gmax = __uint_as_float(*gmaxbits);
        float margin = 2.0f * params[0] * nrm[i] * gmax + 100.0f + 1e-5f * Lx1;
        if (!(Lx1 - alt > margin)) hard = true;    // NaN-safe: NaN -> hard
    }
    if (hard) {
        if (lane == 0) { int p = atomicAdd(hardcnt, 1); hardlist[p] = i; }
        return;
    }
    // easy: softmax exactly one-hot at candidate rank f -> out = celu[f] (precomputed)
    float4 v = ((const float4*)&celu[(ll)f * FOUT])[lane];
    ((float4*)&out[(ll)i * FOUT])[lane] = v;
}

// ---------------- kernel 5a: hard rows — logits + row max (parallel over chunks) ----------------
__global__ __launch_bounds__(256) void hardA_kernel(
    const float* __restrict__ Wh, const float* __restrict__ params,
    const int* __restrict__ adj, const float* __restrict__ x1, const float* __restrict__ x2,
    const float* __restrict__ w1, const float* __restrict__ w2,
    const int* __restrict__ hardcnt, const int* __restrict__ hardlist,
    float* __restrict__ ebuf, unsigned* __restrict__ rowmaxenc) {
    const int h = blockIdx.x >> 5;          // 32 chunks of 256 columns
    const int chunk = blockIdx.x & 31;
    const int nh = min(*hardcnt, HMAX);
    if (h >= nh) return;
    const int i = hardlist[h];
    __shared__ float Whi[FOUT];
    __shared__ float red[4];
    const int t = threadIdx.x;
    Whi[t] = Wh[(ll)i * FOUT + t];
    __syncthreads();
    const int j = (chunk << 8) + t;
    const float4* wi4 = (const float4*)Whi;
    const float4* wr  = (const float4*)&Wh[(ll)j * FOUT];
    float s = 0.f;
#pragma unroll 8
    for (int f = 0; f < 64; ++f) {
        float4 a = wi4[f], b = wr[f];
        s = fmaf(a.x, b.x, fmaf(a.y, b.y, fmaf(a.z, b.z, fmaf(a.w, b.w, s))));
    }
    float ev = fmaf(params[0], s, params[1]);
    ev = fmaf(w1[i], x1[j], ev);
    ev = fmaf(w2[i], x2[j], ev);
    ev = (adj[(ll)i * N + j] > 0) ? ev : NEGV;
    ebuf[h * N + j] = ev;
    float mx = ev;
#pragma unroll
    for (int off = 1; off < 64; off <<= 1) mx = fmaxf(mx, __shfl_xor(mx, off, 64));
    if ((t & 63) == 0) red[t >> 6] = mx;
    __syncthreads();
    if (t == 0) {
        mx = fmaxf(fmaxf(red[0], red[1]), fmaxf(red[2], red[3]));
        unsigned u = __float_as_uint(mx);
        unsigned enc = (u & 0x80000000u) ? ~u : (u | 0x80000000u);
        atomicMax(&rowmaxenc[h], enc);
    }
}

// ---------------- kernel 5b: hard rows — exp/sum + partial PV ----------------
__global__ __launch_bounds__(256) void hardB_kernel(
    const float* __restrict__ Wh, const int* __restrict__ hardcnt,
    const float* __restrict__ ebuf, const unsigned* __restrict__ rowmaxenc,
    float* __restrict__ rowsum, float* __restrict__ acc) {
    const int h = blockIdx.x >> 5;
    const int chunk = blockIdx.x & 31;
    const int nh = min(*hardcnt, HMAX);
    if (h >= nh) return;
    const int t = threadIdx.x;
    unsigned enc = rowmaxenc[h];
    unsigned u = (enc & 0x80000000u) ? (enc & 0x7fffffffu) : ~enc;
    const float mx = __uint_as_float(u);
    const int j = (chunk << 8) + t;
    float p = expf(ebuf[h * N + j] - mx);
    __shared__ float pl[256];
    pl[t] = p;
    float ps = p;
#pragma unroll
    for (int off = 1; off < 64; off <<= 1) ps += __shfl_xor(ps, off, 64);
    if ((t & 63) == 0) atomicAdd(&rowsum[h], ps);
    __syncthreads();
    float o = 0.f;
    const float* base = &Wh[(ll)(chunk << 8) * FOUT + t];
#pragma unroll 4
    for (int jj = 0; jj < 256; ++jj) o = fmaf(pl[jj], base[(ll)jj * FOUT], o);
    atomicAdd(&acc[h * FOUT + t], o);
}

// ---------------- kernel 5c: hard rows — normalize+store (blocks<HMAX) + serial overflow tail ----------------
__global__ __launch_bounds__(256) void hardCtail_kernel(
    const float* __restrict__ Wh, const float* __restrict__ params,
    const int* __restrict__ adj, const float* __restrict__ x1, const float* __restrict__ x2,
    const float* __restrict__ w1, const float* __restrict__ w2,
    const int* __restrict__ hardcnt, const int* __restrict__ hardlist,
    const float* __restrict__ rowsum, const float* __restrict__ acc,
    float* __restrict__ out) {
    __shared__ float Whi[FOUT];
    __shared__ float ebuf[N];
    __shared__ float red[16];
    const int t = threadIdx.x;
    const int nh = *hardcnt;
    if (blockIdx.x < HMAX) {
        const int h = blockIdx.x;
        if (h >= min(nh, HMAX)) return;
        const int i = hardlist[h];
        float o = acc[h * FOUT + t] / rowsum[h];
        out[(ll)i * FOUT + t] = o > 0.f ? o : expm1f(o);
        return;
    }
    // overflow tail: h >= HMAX (normally no-op)
    for (int h = HMAX + (blockIdx.x - HMAX); h < nh; h += gridDim.x - HMAX) {
        const int i = hardlist[h];
        __syncthreads();
        Whi[t] = Wh[(ll)i * FOUT + t];
        __syncthreads();
        const float aC = params[0], cA = params[1], w1i = w1[i], w2i = w2[i];
        const float4* wi4 = (const float4*)Whi;
        for (int j0 = 0; j0 < N; j0 += 256) {
            int j = j0 + t;
            const float4* wr = (const float4*)&Wh[(ll)j * FOUT];
            float s = 0.f;
#pragma unroll 8
            for (int f = 0; f < 64; ++f) {
                float4 a = wi4[f], b = wr[f];
                s = fmaf(a.x, b.x, fmaf(a.y, b.y, fmaf(a.z, b.z, fmaf(a.w, b.w, s))));
            }
            float ev = fmaf(aC, s, cA);
            ev = fmaf(w1i, x1[j], ev);
            ev = fmaf(w2i, x2[j], ev);
            ebuf[j] = (adj[(ll)i * N + j] > 0) ? ev : NEGV;
        }
        __syncthreads();
        float mx = -INFINITY;
        for (int j = t; j < N; j += 256) mx = fmaxf(mx, ebuf[j]);
#pragma unroll
        for (int off = 1; off < 64; off <<= 1) mx = fmaxf(mx, __shfl_xor(mx, off, 64));
        if ((t & 63) == 0) red[t >> 6] = mx;
        __syncthreads();
        mx = fmaxf(fmaxf(red[0], red[1]), fmaxf(red[2], red[3]));
        float ls = 0.f;
        for (int j = t; j < N; j += 256) {
            float p = expf(ebuf[j] - mx);
            ebuf[j] = p;
            ls += p;
        }
#pragma unroll
        for (int off = 1; off < 64; off <<= 1) ls += __shfl_xor(ls, off, 64);
        if ((t & 63) == 0) red[8 + (t >> 6)] = ls;
        __syncthreads();
        ls = (red[8] + red[9]) + (red[10] + red[11]);
        float o0 = 0.f, o1 = 0.f, o2 = 0.f, o3 = 0.f;
        for (int j = 0; j < N; j += 4) {
            o0 = fmaf(ebuf[j + 0], Wh[(ll)(j + 0) * FOUT + t], o0);
            o1 = fmaf(ebuf[j + 1], Wh[(ll)(j + 1) * FOUT + t], o1);
            o2 = fmaf(ebuf[j + 2], Wh[(ll)(j + 2) * FOUT + t], o2);
            o3 = fmaf(ebuf[j + 3], Wh[(ll)(j + 3) * FOUT + t], o3);
        }
        float o = ((o0 + o1) + (o2 + o3)) / ls;
        out[(ll)i * FOUT + t] = o > 0.f ? o : expm1f(o);
    }
}

// ---------------- launch ----------------
extern "C" void kernel_launch(void* const* d_in, const int* in_sizes, int n_in,
                              void* d_out, int out_size, void* d_ws, size_t ws_size,
                              hipStream_t stream) {
    const float* h   = (const float*)d_in[0];
    const float* W   = (const float*)d_in[1];
    const float* Mui = (const float*)d_in[2];
    const int*   adj = (const int*)d_in[3];
    float* out = (float*)d_out;

    float* ws = (float*)d_ws;
    float* Wh     = ws;                         // 8192*256
    float* t1a    = Wh + N * FOUT;              // N
    float* x1     = t1a + N;
    float* x2     = x1 + N;
    float* w1     = x2 + N;
    float* w2     = w1 + N;
    float* nrm    = w2 + N;
    float* params = nrm + N;                    // 8
    float* ct1    = params + 8;                 // NCAND
    float* cx1    = ct1 + NCAND;
    float* cx2    = cx1 + NCAND;
    float* ubx    = cx2 + NCAND;                // 2
    float* o1v    = ubx + 2;                    // 1024
    float* celu   = o1v + 1024;                 // NCAND*FOUT = 4096
    float* ebuf   = celu + NCAND * FOUT;        // HMAX*N
    float* acc    = ebuf + HMAX * N;            // HMAX*FOUT
    float* rowsum = acc + HMAX * FOUT;          // HMAX
    int*   o1i       = (int*)(rowsum + HMAX);   // 1024
    int*   cidx      = o1i + 1024;              // NCAND
    int*   hardcnt   = cidx + NCAND;            // 1
    unsigned* gmaxb  = (unsigned*)(hardcnt + 1);// 1
    unsigned* rowmaxenc = gmaxb + 1;            // HMAX
    int*   hardlist  = (int*)(rowmaxenc + HMAX);// N

    wh_gemm<<<dim3(FOUT / 64, N / 64), 256, 0, stream>>>(h, W, Wh, gmaxb);
    factors2_kernel<<<N / 4, 256, 0, stream>>>(Wh, Mui, params, t1a, x1, x2, w1, w2, nrm);
    redtopk1_kernel<<<64, 64, 0, stream>>>(t1a, nrm, gmaxb, o1v, o1i);
    topk2_kernel<<<1, 1024, 0, stream>>>(o1v, o1i, t1a, x1, x2, Wh,
                                         cidx, ct1, cx1, cx2, ubx, hardcnt,
                                         acc, rowsum, rowmaxenc, celu);
    classify_kernel<<<N / 4, 256, 0, stream>>>(celu, params, adj, cidx, ct1, cx1, cx2, ubx,
                                               w1, w2, nrm, gmaxb, hardcnt, hardlist, out);
    hardA_kernel<<<32 * HMAX, 256, 0, stream>>>(Wh, params, adj, x1, x2, w1, w2,
                                                hardcnt, hardlist, ebuf, rowmaxenc);
    hardB_kernel<<<32 * HMAX, 256, 0, stream>>>(Wh, hardcnt, ebuf, rowmaxenc, rowsum, acc);
    hardCtail_kernel<<<HMAX + 128, 256, 0, stream>>>(Wh, params, adj, x1, x2, w1, w2,
                                                     hardcnt, hardlist, rowsum, acc, out);
    (void)n_in; (void)in_sizes; (void)out_size; (void)ws_size;
}